// Round 6
// baseline (374.086 us; speedup 1.0000x reference)
//
#include <hip/hip_runtime.h>

// Varifold loss, round 6: same MFMA math as R5 (16x16x32 f16 exact hi/lo
// split), restructured pair loop: divergence-free loads via a zero page
// (q>=2 lanes read zeros from a dedicated region, pointer increment 0),
// 2 j-tiles per iteration, everything in VGPRs.
//
// t_ij  = cq_i + cq_j + TG*<C_i,C_j>   (TG = 2*gamma*log2e)
// d_ij  = <m_i,m_j>, m = Nn*sqrt(L);  pair term = exp2(t)*d^2.

#define NVERT 5023
#define NFACE 9976
#define BATCH 4
#define HALFP 9984            // per-mesh faces padded to x16
#define NTP   (2 * HALFP)     // 19968 faces per batch
#define NJT   1248            // j-tiles of 16
#define NPAN  156             // i-panels of 128
#define SPLITS 4

#define RECH 64               // halfs per face record (128 B)
#define OTA 0
#define ODA 16
#define OTB 32
#define ODB 48
#define ZHALFS 2048           // 4 KB zero region after records

constexpr float GAMMA = 1.0f / (0.03f * 0.03f);
constexpr float LOG2E = 1.4426950408889634f;
constexpr float EPSV  = 1e-12f;

typedef _Float16 half8_t __attribute__((ext_vector_type(8)));
typedef float    f32x4   __attribute__((ext_vector_type(4)));

__global__ __launch_bounds__(256)
void face_quant_kernel(const float* __restrict__ pred,
                       const float* __restrict__ targ,
                       const int*   __restrict__ faces,
                       _Float16*    __restrict__ fd,
                       float*       __restrict__ out) {
    int idx = blockIdx.x * 256 + threadIdx.x;
    if (idx == 0) out[0] = 0.0f;
    const int total = BATCH * NTP;

    if (idx >= total) {                       // zero page writers
        int zi = idx - total;
        if (zi < ZHALFS / 8) {
            half8_t z = {};
            *(half8_t*)(fd + (size_t)total * RECH + zi * 8) = z;
        }
        return;
    }

    int b     = idx / NTP;
    int s     = idx - b * NTP;
    int which = (s >= HALFP) ? 1 : 0;
    int f     = s - which * HALFP;

    _Float16* rec = fd + (size_t)idx * RECH;

    if (f >= NFACE) {
        half8_t z = {};
        #pragma unroll
        for (int k = 0; k < 8; ++k) *(half8_t*)(rec + k * 8) = z;
        return;
    }

    const float* V = (which ? targ : pred) + (size_t)b * NVERT * 3;
    int i0 = faces[f * 3 + 0];
    int i1 = faces[f * 3 + 1];
    int i2 = faces[f * 3 + 2];

    float v0x = V[i0*3+0], v0y = V[i0*3+1], v0z = V[i0*3+2];
    float v1x = V[i1*3+0], v1y = V[i1*3+1], v1z = V[i1*3+2];
    float v2x = V[i2*3+0], v2y = V[i2*3+1], v2z = V[i2*3+2];

    const float third = 1.0f / 3.0f;
    float cx = (v0x + v1x + v2x) * third;
    float cy = (v0y + v1y + v2y) * third;
    float cz = (v0z + v1z + v2z) * third;

    float e1x = v1x - v0x, e1y = v1y - v0y, e1z = v1z - v0z;
    float e2x = v2x - v0x, e2y = v2y - v0y, e2z = v2z - v0z;

    float nx = 0.5f * (e1y * e2z - e1z * e2y);
    float ny = 0.5f * (e1z * e2x - e1x * e2z);
    float nz = 0.5f * (e1x * e2y - e1y * e2x);

    float L   = sqrtf(nx*nx + ny*ny + nz*nz);
    float inv = 1.0f / fmaxf(L, EPSV);
    float sc  = inv * sqrtf(L);            // m = Nn*sqrt(L)
    float mx = nx * sc, my = ny * sc, mz = nz * sc;

    const float TG = 2.0f * GAMMA * LOG2E;
    float tgx = TG * cx, tgy = TG * cy, tgz = TG * cz;
    float cq  = -GAMMA * LOG2E * (cx*cx + cy*cy + cz*cz);

    _Float16 TGxh = (_Float16)tgx; _Float16 TGxl = (_Float16)(tgx - (float)TGxh);
    _Float16 TGyh = (_Float16)tgy; _Float16 TGyl = (_Float16)(tgy - (float)TGyh);
    _Float16 TGzh = (_Float16)tgz; _Float16 TGzl = (_Float16)(tgz - (float)TGzh);
    _Float16 Cxh  = (_Float16)cx;  _Float16 Cxl  = (_Float16)(cx  - (float)Cxh);
    _Float16 Cyh  = (_Float16)cy;  _Float16 Cyl  = (_Float16)(cy  - (float)Cyh);
    _Float16 Czh  = (_Float16)cz;  _Float16 Czl  = (_Float16)(cz  - (float)Czh);
    _Float16 cqh  = (_Float16)cq;  _Float16 cql  = (_Float16)(cq  - (float)cqh);
    _Float16 mxh  = (_Float16)mx;  _Float16 mxl  = (_Float16)(mx  - (float)mxh);
    _Float16 myh  = (_Float16)my;  _Float16 myl  = (_Float16)(my  - (float)myh);
    _Float16 mzh  = (_Float16)mz;  _Float16 mzl  = (_Float16)(mz  - (float)mzh);
    _Float16 one  = (_Float16)1.0f;
    _Float16 zz   = (_Float16)0.0f;

    half8_t ta0 = {TGxh, TGyh, TGzh, TGxl, TGyl, TGzl, TGxh, TGyh};
    half8_t ta1 = {TGzh, TGxl, TGyl, TGzl, cqh,  cql,  one,  one };
    half8_t da0 = {mxh,  myh,  mzh,  mxl,  myl,  mzl,  mxh,  myh };
    half8_t da1 = {mzh,  mxl,  myl,  mzl,  zz,   zz,   zz,   zz  };
    half8_t tb0 = {Cxh,  Cyh,  Czh,  Cxh,  Cyh,  Czh,  Cxl,  Cyl };
    half8_t tb1 = {Czl,  Cxl,  Cyl,  Czl,  one,  one,  cqh,  cql };
    half8_t db0 = {mxh,  myh,  mzh,  mxh,  myh,  mzh,  mxl,  myl };
    half8_t db1 = {mzl,  mxl,  myl,  mzl,  zz,   zz,   zz,   zz  };

    *(half8_t*)(rec + OTA + 0) = ta0;  *(half8_t*)(rec + OTA + 8) = ta1;
    *(half8_t*)(rec + ODA + 0) = da0;  *(half8_t*)(rec + ODA + 8) = da1;
    *(half8_t*)(rec + OTB + 0) = tb0;  *(half8_t*)(rec + OTB + 8) = tb1;
    *(half8_t*)(rec + ODB + 0) = db0;  *(half8_t*)(rec + ODB + 8) = db1;
}

__device__ __forceinline__ half8_t ld8(const _Float16* p) {
    return *(const half8_t*)p;
}

__global__ __launch_bounds__(256)
void pair_sum_kernel(const _Float16* __restrict__ fd,
                     float*          __restrict__ out) {
    const int b       = blockIdx.z;
    const int pairIdx = blockIdx.x / SPLITS;     // 0..77
    const int s       = blockIdx.x % SPLITS;

    const _Float16* base  = fd + (size_t)b * NTP * RECH;
    const _Float16* zpage = fd + (size_t)BATCH * NTP * RECH;

    const int  lane  = threadIdx.x & 63;
    const int  w     = threadIdx.x >> 6;
    const int  q     = lane >> 4;
    const int  fcol  = lane & 15;
    const bool qlive = (q < 2);

    float acc = 0.0f;

    #pragma unroll 1
    for (int h = 0; h < 2; ++h) {
        const int   P   = h ? (NPAN - 1 - pairIdx) : pairIdx;
        const int   jb8 = P * 8;
        const float si  = (P < NPAN / 2) ? 1.0f : -1.0f;

        // A-frags: rows P*128 + w*16 and +64
        const _Float16* r0  = base + (size_t)(P * 128 + w * 16 + fcol) * RECH;
        const _Float16* r1  = r0 + (size_t)64 * RECH;
        const _Float16* pa0 = qlive ? r0 : zpage;
        const _Float16* pa1 = qlive ? r1 : zpage;
        half8_t aT0 = ld8(pa0 + OTA + q * 8);
        half8_t aD0 = ld8(pa0 + ODA + q * 8);
        half8_t aT1 = ld8(pa1 + OTA + q * 8);
        half8_t aD1 = ld8(pa1 + ODA + q * 8);

        // j pointer: tile pair (tja, tja+1), tja = jb8 + 2s + 8k
        const _Float16* jrow = base + (size_t)((jb8 + 2 * s) * 16 + fcol) * RECH;
        const _Float16* pj   = qlive ? jrow : zpage;
        const size_t    jinc = qlive ? (size_t)(8 * 16 * RECH) : 0;

        const int iters = NJT / 8 - P;          // 156 - P

        #pragma unroll 1
        for (int k = 0; k < iters; ++k) {
            half8_t bTa = ld8(pj + OTB + q * 8);
            half8_t bDa = ld8(pj + ODB + q * 8);
            half8_t bTb = ld8(pj + 16 * RECH + OTB + q * 8);
            half8_t bDb = ld8(pj + 16 * RECH + ODB + q * 8);
            pj += jinc;

            f32x4 z = {0.f, 0.f, 0.f, 0.f};
            f32x4 T0a = __builtin_amdgcn_mfma_f32_16x16x32_f16(aT0, bTa, z, 0, 0, 0);
            f32x4 D0a = __builtin_amdgcn_mfma_f32_16x16x32_f16(aD0, bDa, z, 0, 0, 0);
            f32x4 T1a = __builtin_amdgcn_mfma_f32_16x16x32_f16(aT1, bTa, z, 0, 0, 0);
            f32x4 D1a = __builtin_amdgcn_mfma_f32_16x16x32_f16(aD1, bDa, z, 0, 0, 0);
            f32x4 T0b = __builtin_amdgcn_mfma_f32_16x16x32_f16(aT0, bTb, z, 0, 0, 0);
            f32x4 D0b = __builtin_amdgcn_mfma_f32_16x16x32_f16(aD0, bDb, z, 0, 0, 0);
            f32x4 T1b = __builtin_amdgcn_mfma_f32_16x16x32_f16(aT1, bTb, z, 0, 0, 0);
            f32x4 D1b = __builtin_amdgcn_mfma_f32_16x16x32_f16(aD1, bDb, z, 0, 0, 0);

            float tsa = 0.f, tsb = 0.f;
            #pragma unroll
            for (int r = 0; r < 4; ++r) {
                tsa = fmaf(__builtin_amdgcn_exp2f(T0a[r]), D0a[r] * D0a[r], tsa);
                tsa = fmaf(__builtin_amdgcn_exp2f(T1a[r]), D1a[r] * D1a[r], tsa);
                tsb = fmaf(__builtin_amdgcn_exp2f(T0b[r]), D0b[r] * D0b[r], tsb);
                tsb = fmaf(__builtin_amdgcn_exp2f(T1b[r]), D1b[r] * D1b[r], tsb);
            }

            int   tja = jb8 + 2 * s + 8 * k;
            float wgt = (k == 0) ? 1.0f : 2.0f;
            float fa  = ((tja     < NJT / 2) ? si : -si) * wgt * (1.0f / BATCH);
            float fb  = ((tja + 1 < NJT / 2) ? si : -si) * wgt * (1.0f / BATCH);
            acc = fmaf(fa, tsa, acc);
            acc = fmaf(fb, tsb, acc);
        }
    }

    #pragma unroll
    for (int off = 32; off > 0; off >>= 1)
        acc += __shfl_down(acc, off, 64);

    __shared__ float wsum[4];
    if (lane == 0) wsum[w] = acc;
    __syncthreads();
    if (threadIdx.x == 0)
        atomicAdd(out, wsum[0] + wsum[1] + wsum[2] + wsum[3]);
}

extern "C" void kernel_launch(void* const* d_in, const int* in_sizes, int n_in,
                              void* d_out, int out_size, void* d_ws, size_t ws_size,
                              hipStream_t stream) {
    const float* pred  = (const float*)d_in[0];
    const float* targ  = (const float*)d_in[1];
    const int*   faces = (const int*)d_in[2];
    float*       out   = (float*)d_out;
    _Float16*    fd    = (_Float16*)d_ws;   // records 10.22 MB + 4 KB zero page

    const int totalThreads = BATCH * NTP + ZHALFS / 8;   // faces + zero writers
    face_quant_kernel<<<(totalThreads + 255) / 256, 256, 0, stream>>>(
        pred, targ, faces, fd, out);

    dim3 grid((NPAN / 2) * SPLITS, 1, BATCH);   // 312 x 1 x 4
    pair_sum_kernel<<<grid, 256, 0, stream>>>(fd, out);
}

// Round 7
// 178.589 us; speedup vs baseline: 2.0947x; 2.0947x over previous
//
#include <hip/hip_runtime.h>

// Varifold loss, round 7: 32x32x16 f16 MFMA (K=16 exactly matches the
// split operands -> all 64 lanes live, no zero page), explicit branchless
// register prefetch of next j-chunk, SPLITS=8 for occupancy.
//
// t_ij = cq_i + cq_j + TG*<C_i,C_j>;  d_ij = <m_i,m_j>;  term = exp2(t)*d^2.
// A-operand (row face i), K=16: [TGh(3),TGl(3),TGh(3),TGl(3),cqh,cql,1,1]
// B-operand (col face j), K=16: [Ch(3),Ch(3),Cl(3),Cl(3),1,1,cqh,cql]
// d: A=[mh,ml,mh,ml,0^4], B=[mh,mh,ml,ml,0^4]  (exact (mh+ml).(mh+ml))
//
// Records: Arec[face] = 32 halfs [tA(16), dA(16)]; Brec likewise. Lane
// loads its 8-half k-slice: col=lane&31, koff=(lane>>5)*8.

#define NVERT 5023
#define NFACE 9976
#define BATCH 4
#define HALFP 9984             // per-mesh faces padded to x128
#define NTP   (2 * HALFP)      // 19968 faces per batch
#define NTOT  (BATCH * NTP)    // 79872
#define NCH   624              // j-chunks of 32 per batch
#define NPAN  156              // i-panels of 128
#define SPLITS 8

constexpr float GAMMA = 1.0f / (0.03f * 0.03f);
constexpr float LOG2E = 1.4426950408889634f;
constexpr float EPSV  = 1e-12f;

typedef _Float16 half8_t  __attribute__((ext_vector_type(8)));
typedef float    f32x16   __attribute__((ext_vector_type(16)));

__global__ __launch_bounds__(256)
void face_quant_kernel(const float* __restrict__ pred,
                       const float* __restrict__ targ,
                       const int*   __restrict__ faces,
                       _Float16*    __restrict__ fd,
                       float*       __restrict__ out) {
    int idx = blockIdx.x * 256 + threadIdx.x;
    if (idx == 0) out[0] = 0.0f;
    if (idx >= NTOT) return;

    int b     = idx / NTP;
    int s     = idx - b * NTP;
    int which = (s >= HALFP) ? 1 : 0;
    int f     = s - which * HALFP;

    _Float16* arec = fd + (size_t)idx * 32;
    _Float16* brec = fd + (size_t)NTOT * 32 + (size_t)idx * 32;

    if (f >= NFACE) {
        half8_t z = {};
        *(half8_t*)(arec + 0) = z; *(half8_t*)(arec + 8)  = z;
        *(half8_t*)(arec + 16) = z; *(half8_t*)(arec + 24) = z;
        *(half8_t*)(brec + 0) = z; *(half8_t*)(brec + 8)  = z;
        *(half8_t*)(brec + 16) = z; *(half8_t*)(brec + 24) = z;
        return;
    }

    const float* V = (which ? targ : pred) + (size_t)b * NVERT * 3;
    int i0 = faces[f * 3 + 0];
    int i1 = faces[f * 3 + 1];
    int i2 = faces[f * 3 + 2];

    float v0x = V[i0*3+0], v0y = V[i0*3+1], v0z = V[i0*3+2];
    float v1x = V[i1*3+0], v1y = V[i1*3+1], v1z = V[i1*3+2];
    float v2x = V[i2*3+0], v2y = V[i2*3+1], v2z = V[i2*3+2];

    const float third = 1.0f / 3.0f;
    float cx = (v0x + v1x + v2x) * third;
    float cy = (v0y + v1y + v2y) * third;
    float cz = (v0z + v1z + v2z) * third;

    float e1x = v1x - v0x, e1y = v1y - v0y, e1z = v1z - v0z;
    float e2x = v2x - v0x, e2y = v2y - v0y, e2z = v2z - v0z;

    float nx = 0.5f * (e1y * e2z - e1z * e2y);
    float ny = 0.5f * (e1z * e2x - e1x * e2z);
    float nz = 0.5f * (e1x * e2y - e1y * e2x);

    float L   = sqrtf(nx*nx + ny*ny + nz*nz);
    float inv = 1.0f / fmaxf(L, EPSV);
    float sc  = inv * sqrtf(L);            // m = Nn*sqrt(L)
    float mx = nx * sc, my = ny * sc, mz = nz * sc;

    const float TG = 2.0f * GAMMA * LOG2E;
    float tgx = TG * cx, tgy = TG * cy, tgz = TG * cz;
    float cq  = -GAMMA * LOG2E * (cx*cx + cy*cy + cz*cz);

    _Float16 TGxh = (_Float16)tgx; _Float16 TGxl = (_Float16)(tgx - (float)TGxh);
    _Float16 TGyh = (_Float16)tgy; _Float16 TGyl = (_Float16)(tgy - (float)TGyh);
    _Float16 TGzh = (_Float16)tgz; _Float16 TGzl = (_Float16)(tgz - (float)TGzh);
    _Float16 Cxh  = (_Float16)cx;  _Float16 Cxl  = (_Float16)(cx  - (float)Cxh);
    _Float16 Cyh  = (_Float16)cy;  _Float16 Cyl  = (_Float16)(cy  - (float)Cyh);
    _Float16 Czh  = (_Float16)cz;  _Float16 Czl  = (_Float16)(cz  - (float)Czh);
    _Float16 cqh  = (_Float16)cq;  _Float16 cql  = (_Float16)(cq  - (float)cqh);
    _Float16 mxh  = (_Float16)mx;  _Float16 mxl  = (_Float16)(mx  - (float)mxh);
    _Float16 myh  = (_Float16)my;  _Float16 myl  = (_Float16)(my  - (float)myh);
    _Float16 mzh  = (_Float16)mz;  _Float16 mzl  = (_Float16)(mz  - (float)mzh);
    _Float16 one  = (_Float16)1.0f;
    _Float16 zz   = (_Float16)0.0f;

    half8_t ta0 = {TGxh, TGyh, TGzh, TGxl, TGyl, TGzl, TGxh, TGyh};
    half8_t ta1 = {TGzh, TGxl, TGyl, TGzl, cqh,  cql,  one,  one };
    half8_t da0 = {mxh,  myh,  mzh,  mxl,  myl,  mzl,  mxh,  myh };
    half8_t da1 = {mzh,  mxl,  myl,  mzl,  zz,   zz,   zz,   zz  };
    half8_t tb0 = {Cxh,  Cyh,  Czh,  Cxh,  Cyh,  Czh,  Cxl,  Cyl };
    half8_t tb1 = {Czl,  Cxl,  Cyl,  Czl,  one,  one,  cqh,  cql };
    half8_t db0 = {mxh,  myh,  mzh,  mxh,  myh,  mzh,  mxl,  myl };
    half8_t db1 = {mzl,  mxl,  myl,  mzl,  zz,   zz,   zz,   zz  };

    *(half8_t*)(arec + 0)  = ta0;  *(half8_t*)(arec + 8)  = ta1;
    *(half8_t*)(arec + 16) = da0;  *(half8_t*)(arec + 24) = da1;
    *(half8_t*)(brec + 0)  = tb0;  *(half8_t*)(brec + 8)  = tb1;
    *(half8_t*)(brec + 16) = db0;  *(half8_t*)(brec + 24) = db1;
}

__device__ __forceinline__ half8_t ld8(const _Float16* p) {
    return *(const half8_t*)p;
}

__global__ __launch_bounds__(256, 4)
void pair_sum_kernel(const _Float16* __restrict__ fd,
                     float*          __restrict__ out) {
    const int b       = blockIdx.z;
    const int pairIdx = blockIdx.x / SPLITS;     // 0..77
    const int s       = blockIdx.x % SPLITS;

    const _Float16* Arec = fd;
    const _Float16* Brec = fd + (size_t)NTOT * 32;

    const int lane = threadIdx.x & 63;
    const int w    = threadIdx.x >> 6;
    const int col  = lane & 31;
    const int koff = (lane >> 5) * 8;

    const size_t bface = (size_t)b * NTP;
    const size_t JSTEP = (size_t)SPLITS * 32 * 32;   // 8 chunks x 32 faces x 32 halfs

    float acc = 0.0f;

    #pragma unroll 1
    for (int h = 0; h < 2; ++h) {
        const int   P  = h ? (NPAN - 1 - pairIdx) : pairIdx;
        const int   c0 = 4 * P;
        const float si = (P < NPAN / 2) ? 1.0f : -1.0f;
        const int   iters = (NCH - c0 - s + 7) >> 3;
        if (iters <= 0) continue;

        // A-frags: i-face = P*128 + w*32 + col
        const _Float16* ap = Arec + (bface + (size_t)(P * 128 + w * 32 + col)) * 32 + koff;
        half8_t aT = ld8(ap);
        half8_t aD = ld8(ap + 16);

        // B pointer for first chunk jc = c0 + s
        const _Float16* pB = Brec + (bface + (size_t)((c0 + s) * 32 + col)) * 32 + koff;
        half8_t bT = ld8(pB);
        half8_t bD = ld8(pB + 16);

        #pragma unroll 1
        for (int k = 0; k < iters; ++k) {
            // branchless prefetch of next chunk (clamped in-bounds)
            const _Float16* pN = (k + 1 < iters) ? (pB + JSTEP) : pB;
            half8_t nT = ld8(pN);
            half8_t nD = ld8(pN + 16);
            pB = pN;

            f32x16 z = {};
            f32x16 T = __builtin_amdgcn_mfma_f32_32x32x16_f16(aT, bT, z, 0, 0, 0);
            f32x16 D = __builtin_amdgcn_mfma_f32_32x32x16_f16(aD, bD, z, 0, 0, 0);

            float ts0 = 0.f, ts1 = 0.f;
            #pragma unroll
            for (int r = 0; r < 16; r += 2) {
                float e0 = __builtin_amdgcn_exp2f(T[r]);
                float d0 = D[r];
                ts0 = fmaf(e0, d0 * d0, ts0);
                float e1 = __builtin_amdgcn_exp2f(T[r + 1]);
                float d1 = D[r + 1];
                ts1 = fmaf(e1, d1 * d1, ts1);
            }

            const int   jc  = c0 + s + 8 * k;
            const float sj  = (jc < NCH / 2) ? si : -si;
            const float wgt = (k == 0 && s < 4) ? 1.0f : 2.0f;
            acc = fmaf(sj * wgt * (1.0f / BATCH), ts0 + ts1, acc);

            bT = nT; bD = nD;
        }
    }

    #pragma unroll
    for (int off = 32; off > 0; off >>= 1)
        acc += __shfl_down(acc, off, 64);

    __shared__ float wsum[4];
    if (lane == 0) wsum[w] = acc;
    __syncthreads();
    if (threadIdx.x == 0)
        atomicAdd(out, wsum[0] + wsum[1] + wsum[2] + wsum[3]);
}

extern "C" void kernel_launch(void* const* d_in, const int* in_sizes, int n_in,
                              void* d_out, int out_size, void* d_ws, size_t ws_size,
                              hipStream_t stream) {
    const float* pred  = (const float*)d_in[0];
    const float* targ  = (const float*)d_in[1];
    const int*   faces = (const int*)d_in[2];
    float*       out   = (float*)d_out;
    _Float16*    fd    = (_Float16*)d_ws;   // 2 arrays x 79872 faces x 64 B = 10.2 MB

    face_quant_kernel<<<(NTOT + 255) / 256, 256, 0, stream>>>(
        pred, targ, faces, fd, out);

    dim3 grid((NPAN / 2) * SPLITS, 1, BATCH);   // 624 x 1 x 4 = 2496 blocks
    pair_sum_kernel<<<grid, 256, 0, stream>>>(fd, out);
}

// Round 8
// 171.771 us; speedup vs baseline: 2.1778x; 1.0397x over previous
//
#include <hip/hip_runtime.h>

// Varifold loss, round 8: R7's 32x32x16 f16 MFMA structure + depth-2
// software pipeline: iteration k issues MFMA(k+1), prefetches B(k+2),
// and runs the epilogue (exp2/d^2/acc) on MFMA results from k — hiding
// MFMA + load latency behind the ~200-cy epilogue.
//
// t_ij = cq_i + cq_j + TG*<C_i,C_j>;  d_ij = <m_i,m_j>;  term = exp2(t)*d^2.
// A-op K=16: [TGh(3),TGl(3),TGh(3),TGl(3),cqh,cql,1,1]
// B-op K=16: [Ch(3),Ch(3),Cl(3),Cl(3),1,1,cqh,cql]
// d:  A=[mh,ml,mh,ml,0^4], B=[mh,mh,ml,ml,0^4]   (exact hi/lo split)

#define NVERT 5023
#define NFACE 9976
#define BATCH 4
#define HALFP 9984             // per-mesh faces padded to x128
#define NTP   (2 * HALFP)      // 19968 faces per batch
#define NTOT  (BATCH * NTP)    // 79872
#define NCH   624              // j-chunks of 32 per batch
#define NPAN  156              // i-panels of 128
#define SPLITS 8

constexpr float GAMMA = 1.0f / (0.03f * 0.03f);
constexpr float LOG2E = 1.4426950408889634f;
constexpr float EPSV  = 1e-12f;

typedef _Float16 half8_t  __attribute__((ext_vector_type(8)));
typedef float    f32x16   __attribute__((ext_vector_type(16)));

__global__ __launch_bounds__(256)
void face_quant_kernel(const float* __restrict__ pred,
                       const float* __restrict__ targ,
                       const int*   __restrict__ faces,
                       _Float16*    __restrict__ fd,
                       float*       __restrict__ out) {
    int idx = blockIdx.x * 256 + threadIdx.x;
    if (idx == 0) out[0] = 0.0f;
    if (idx >= NTOT) return;

    int b     = idx / NTP;
    int s     = idx - b * NTP;
    int which = (s >= HALFP) ? 1 : 0;
    int f     = s - which * HALFP;

    _Float16* arec = fd + (size_t)idx * 32;
    _Float16* brec = fd + (size_t)NTOT * 32 + (size_t)idx * 32;

    if (f >= NFACE) {
        half8_t z = {};
        *(half8_t*)(arec + 0) = z; *(half8_t*)(arec + 8)  = z;
        *(half8_t*)(arec + 16) = z; *(half8_t*)(arec + 24) = z;
        *(half8_t*)(brec + 0) = z; *(half8_t*)(brec + 8)  = z;
        *(half8_t*)(brec + 16) = z; *(half8_t*)(brec + 24) = z;
        return;
    }

    const float* V = (which ? targ : pred) + (size_t)b * NVERT * 3;
    int i0 = faces[f * 3 + 0];
    int i1 = faces[f * 3 + 1];
    int i2 = faces[f * 3 + 2];

    float v0x = V[i0*3+0], v0y = V[i0*3+1], v0z = V[i0*3+2];
    float v1x = V[i1*3+0], v1y = V[i1*3+1], v1z = V[i1*3+2];
    float v2x = V[i2*3+0], v2y = V[i2*3+1], v2z = V[i2*3+2];

    const float third = 1.0f / 3.0f;
    float cx = (v0x + v1x + v2x) * third;
    float cy = (v0y + v1y + v2y) * third;
    float cz = (v0z + v1z + v2z) * third;

    float e1x = v1x - v0x, e1y = v1y - v0y, e1z = v1z - v0z;
    float e2x = v2x - v0x, e2y = v2y - v0y, e2z = v2z - v0z;

    float nx = 0.5f * (e1y * e2z - e1z * e2y);
    float ny = 0.5f * (e1z * e2x - e1x * e2z);
    float nz = 0.5f * (e1x * e2y - e1y * e2x);

    float L   = sqrtf(nx*nx + ny*ny + nz*nz);
    float inv = 1.0f / fmaxf(L, EPSV);
    float sc  = inv * sqrtf(L);            // m = Nn*sqrt(L)
    float mx = nx * sc, my = ny * sc, mz = nz * sc;

    const float TG = 2.0f * GAMMA * LOG2E;
    float tgx = TG * cx, tgy = TG * cy, tgz = TG * cz;
    float cq  = -GAMMA * LOG2E * (cx*cx + cy*cy + cz*cz);

    _Float16 TGxh = (_Float16)tgx; _Float16 TGxl = (_Float16)(tgx - (float)TGxh);
    _Float16 TGyh = (_Float16)tgy; _Float16 TGyl = (_Float16)(tgy - (float)TGyh);
    _Float16 TGzh = (_Float16)tgz; _Float16 TGzl = (_Float16)(tgz - (float)TGzh);
    _Float16 Cxh  = (_Float16)cx;  _Float16 Cxl  = (_Float16)(cx  - (float)Cxh);
    _Float16 Cyh  = (_Float16)cy;  _Float16 Cyl  = (_Float16)(cy  - (float)Cyh);
    _Float16 Czh  = (_Float16)cz;  _Float16 Czl  = (_Float16)(cz  - (float)Czh);
    _Float16 cqh  = (_Float16)cq;  _Float16 cql  = (_Float16)(cq  - (float)cqh);
    _Float16 mxh  = (_Float16)mx;  _Float16 mxl  = (_Float16)(mx  - (float)mxh);
    _Float16 myh  = (_Float16)my;  _Float16 myl  = (_Float16)(my  - (float)myh);
    _Float16 mzh  = (_Float16)mz;  _Float16 mzl  = (_Float16)(mz  - (float)mzh);
    _Float16 one  = (_Float16)1.0f;
    _Float16 zz   = (_Float16)0.0f;

    half8_t ta0 = {TGxh, TGyh, TGzh, TGxl, TGyl, TGzl, TGxh, TGyh};
    half8_t ta1 = {TGzh, TGxl, TGyl, TGzl, cqh,  cql,  one,  one };
    half8_t da0 = {mxh,  myh,  mzh,  mxl,  myl,  mzl,  mxh,  myh };
    half8_t da1 = {mzh,  mxl,  myl,  mzl,  zz,   zz,   zz,   zz  };
    half8_t tb0 = {Cxh,  Cyh,  Czh,  Cxh,  Cyh,  Czh,  Cxl,  Cyl };
    half8_t tb1 = {Czl,  Cxl,  Cyl,  Czl,  one,  one,  cqh,  cql };
    half8_t db0 = {mxh,  myh,  mzh,  mxh,  myh,  mzh,  mxl,  myl };
    half8_t db1 = {mzl,  mxl,  myl,  mzl,  zz,   zz,   zz,   zz  };

    *(half8_t*)(arec + 0)  = ta0;  *(half8_t*)(arec + 8)  = ta1;
    *(half8_t*)(arec + 16) = da0;  *(half8_t*)(arec + 24) = da1;
    *(half8_t*)(brec + 0)  = tb0;  *(half8_t*)(brec + 8)  = tb1;
    *(half8_t*)(brec + 16) = db0;  *(half8_t*)(brec + 24) = db1;
}

__device__ __forceinline__ half8_t ld8(const _Float16* p) {
    return *(const half8_t*)p;
}

__global__ __launch_bounds__(256, 4)
void pair_sum_kernel(const _Float16* __restrict__ fd,
                     float*          __restrict__ out) {
    const int b       = blockIdx.z;
    const int pairIdx = blockIdx.x / SPLITS;     // 0..77
    const int s       = blockIdx.x % SPLITS;

    const _Float16* Arec = fd;
    const _Float16* Brec = fd + (size_t)NTOT * 32;

    const int lane = threadIdx.x & 63;
    const int w    = threadIdx.x >> 6;
    const int col  = lane & 31;
    const int koff = (lane >> 5) * 8;

    const size_t bface = (size_t)b * NTP;
    const size_t JSTEP = (size_t)SPLITS * 32 * 32;   // 8 chunks x 32 faces x 32 halfs

    float acc = 0.0f;

    #pragma unroll 1
    for (int h = 0; h < 2; ++h) {
        const int   P  = h ? (NPAN - 1 - pairIdx) : pairIdx;
        const int   c0 = 4 * P;
        const float si = (P < NPAN / 2) ? 1.0f : -1.0f;
        const int   iters = (NCH - c0 - s + 7) >> 3;
        if (iters <= 0) continue;

        // A-frags: i-face = P*128 + w*32 + col
        const _Float16* ap = Arec + (bface + (size_t)(P * 128 + w * 32 + col)) * 32 + koff;
        half8_t aT = ld8(ap);
        half8_t aD = ld8(ap + 16);

        // pipeline prologue: load B(0), MFMA(0), load B(1)
        const _Float16* pB = Brec + (bface + (size_t)((c0 + s) * 32 + col)) * 32 + koff;
        half8_t bT = ld8(pB);
        half8_t bD = ld8(pB + 16);

        f32x16 z  = {};
        f32x16 Tp = __builtin_amdgcn_mfma_f32_32x32x16_f16(aT, bT, z, 0, 0, 0);
        f32x16 Dp = __builtin_amdgcn_mfma_f32_32x32x16_f16(aD, bD, z, 0, 0, 0);

        pB = (iters > 1) ? (pB + JSTEP) : pB;
        bT = ld8(pB);
        bD = ld8(pB + 16);

        #pragma unroll 1
        for (int k = 0; k < iters; ++k) {
            // issue MFMA for chunk k+1 (result discarded when k+1 == iters)
            f32x16 Tn = __builtin_amdgcn_mfma_f32_32x32x16_f16(aT, bT, z, 0, 0, 0);
            f32x16 Dn = __builtin_amdgcn_mfma_f32_32x32x16_f16(aD, bD, z, 0, 0, 0);

            // prefetch B for chunk k+2 (clamped in-bounds)
            const _Float16* pN = (k + 2 < iters) ? (pB + JSTEP) : pB;
            half8_t nT = ld8(pN);
            half8_t nD = ld8(pN + 16);
            pB = pN;

            // epilogue on chunk k's results
            float ts0 = 0.f, ts1 = 0.f;
            #pragma unroll
            for (int r = 0; r < 16; r += 2) {
                float e0 = __builtin_amdgcn_exp2f(Tp[r]);
                float d0 = Dp[r];
                ts0 = fmaf(e0, d0 * d0, ts0);
                float e1 = __builtin_amdgcn_exp2f(Tp[r + 1]);
                float d1 = Dp[r + 1];
                ts1 = fmaf(e1, d1 * d1, ts1);
            }

            const int   jc  = c0 + s + 8 * k;
            const float sj  = (jc < NCH / 2) ? si : -si;
            const float wgt = (k == 0 && s < 4) ? 1.0f : 2.0f;
            acc = fmaf(sj * wgt * (1.0f / BATCH), ts0 + ts1, acc);

            Tp = Tn; Dp = Dn;
            bT = nT; bD = nD;
        }
    }

    #pragma unroll
    for (int off = 32; off > 0; off >>= 1)
        acc += __shfl_down(acc, off, 64);

    __shared__ float wsum[4];
    if (lane == 0) wsum[w] = acc;
    __syncthreads();
    if (threadIdx.x == 0)
        atomicAdd(out, wsum[0] + wsum[1] + wsum[2] + wsum[3]);
}

extern "C" void kernel_launch(void* const* d_in, const int* in_sizes, int n_in,
                              void* d_out, int out_size, void* d_ws, size_t ws_size,
                              hipStream_t stream) {
    const float* pred  = (const float*)d_in[0];
    const float* targ  = (const float*)d_in[1];
    const int*   faces = (const int*)d_in[2];
    float*       out   = (float*)d_out;
    _Float16*    fd    = (_Float16*)d_ws;   // 2 arrays x 79872 faces x 64 B = 10.2 MB

    face_quant_kernel<<<(NTOT + 255) / 256, 256, 0, stream>>>(
        pred, targ, faces, fd, out);

    dim3 grid((NPAN / 2) * SPLITS, 1, BATCH);   // 624 x 1 x 4 = 2496 blocks
    pair_sum_kernel<<<grid, 256, 0, stream>>>(fd, out);
}